// Round 14
// baseline (149.366 us; speedup 1.0000x reference)
//
#include <hip/hip_runtime.h>

#define NN 100000
#define NE 1600000
#define DIN 128
#define DOUT 32
#define NBUK 391     // ceil(NN/256) buckets of 256 nodes
#define FILLB 512    // edge chunks (512*3125 = NE exactly)
#define CHUNK 3125   // edges per chunk
#define CAP 8192     // max records per bucket staged in LDS (mean 4092, sd ~64)
#define NTILES 6250  // NN/16 MFMA row-tiles
#define XWB 782      // ceil(6250 / 8 waves)

typedef unsigned short ushort_t;
typedef unsigned int uint_t;
typedef _Float16 f16x8 __attribute__((ext_vector_type(8)));
typedef float f32x4 __attribute__((ext_vector_type(4)));

static __device__ __forceinline__ ushort_t f2h_u(float f) {
    _Float16 h = (_Float16)f;
    ushort_t u;
    __builtin_memcpy(&u, &h, 2);
    return u;
}
static __device__ __forceinline__ float h2f(ushort_t us) {
    _Float16 h;
    __builtin_memcpy(&h, &us, 2);
    return (float)h;
}

// ===========================================================================
// k0: blocks 0..7: Wht[c][k] = f16(W[k][c]); blocks 8..203: zero deg.
// ===========================================================================
__global__ __launch_bounds__(512)
void wb_zero_kernel(const float* __restrict__ W, ushort_t* __restrict__ Wht,
                    int* __restrict__ deg) {
    if (blockIdx.x < 8) {
        int i = blockIdx.x * 512 + threadIdx.x;   // 0..4095
        int c = i >> 7, k = i & 127;
        Wht[(size_t)c * DIN + k] = f2h_u(W[(size_t)k * DOUT + c]);
    } else {
        int i = (blockIdx.x - 8) * 512 + threadIdx.x;
        if (i < NN) deg[i] = 0;
    }
}

// ===========================================================================
// k1: FUSED fill + xw.
// Blocks [0, FILLB): per-chunk LDS counting sort of records by bucket, then a
//   fully COALESCED write of the chunk to records[blk*CHUNK..]. Chunk-local
//   offsets -> histmat. Also accumulates per-node deg (global int atomics).
// Blocks [FILLB, FILLB+XWB): xwsh[r] = f16(x[r] @ W) via MFMA (unscaled).
// record = (row << 8) | (col & 255)
// ===========================================================================
__global__ __launch_bounds__(512)
void fill_xw_kernel(const int* __restrict__ row, const int* __restrict__ col,
                    int* __restrict__ histmat, int* __restrict__ deg,
                    unsigned int* __restrict__ records,
                    const float* __restrict__ x, const ushort_t* __restrict__ Wht,
                    ushort_t* __restrict__ xwsh) {
    __shared__ unsigned int stage[CHUNK];   // 12.5 KB
    __shared__ int hist[NBUK];
    __shared__ int s[512];
    __shared__ int lcur[NBUK];
    if (blockIdx.x < FILLB) {
        int t = threadIdx.x, blk = blockIdx.x;
        for (int bb = t; bb < NBUK; bb += 512) hist[bb] = 0;
        __syncthreads();
        int e0 = blk * CHUNK;
        for (int j = t; j < CHUNK; j += 512) {
            int c = col[e0 + j];
            atomicAdd(&hist[c >> 8], 1);
            atomicAdd(&deg[c], 1);          // global in-degree (L2-resident)
        }
        __syncthreads();
        int own = (t < NBUK) ? hist[t] : 0;
        s[t] = own;
        __syncthreads();
        for (int off = 1; off < 512; off <<= 1) {
            int u = (t >= off) ? s[t - off] : 0;
            __syncthreads();
            s[t] += u;
            __syncthreads();
        }
        int excl = s[t] - own;                 // t==NBUK -> 3125 (own=0)
        if (t <= NBUK) histmat[(size_t)blk * (NBUK + 1) + t] = excl;
        if (t < NBUK) lcur[t] = excl;
        __syncthreads();
        for (int j = t; j < CHUNK; j += 512) {
            int e = e0 + j;
            int c = col[e];
            int slot = atomicAdd(&lcur[c >> 8], 1);
            stage[slot] = ((unsigned int)row[e] << 8) | (unsigned int)(c & 255);
        }
        __syncthreads();
        for (int j = t; j < CHUNK; j += 512)
            records[(size_t)blk * CHUNK + j] = stage[j];
        return;
    }
    // ---- xw part: 8 waves x 16 rows ----
    int t = threadIdx.x;
    int wv = t >> 6, lane = t & 63;
    int wtile = (blockIdx.x - FILLB) * 8 + wv;
    if (wtile >= NTILES) return;           // uniform per wave
    int r0 = wtile * 16;
    int rowi = lane & 15;                  // A-row / B-col / D-col
    int kg = lane >> 4;                    // k-group (0..3)

    f16x8 bfrag[2][4];
#pragma unroll
    for (int t2 = 0; t2 < 2; ++t2)
#pragma unroll
        for (int ss = 0; ss < 4; ++ss)
            bfrag[t2][ss] = *(const f16x8*)(Wht + (size_t)(t2 * 16 + rowi) * DIN + ss * 32 + kg * 8);

    const float* __restrict__ xr = x + (size_t)(r0 + rowi) * DIN;
    float4 xa[8];
#pragma unroll
    for (int ss = 0; ss < 4; ++ss) {
        xa[2 * ss]     = *(const float4*)(xr + ss * 32 + kg * 8);
        xa[2 * ss + 1] = *(const float4*)(xr + ss * 32 + kg * 8 + 4);
    }
    f16x8 afrag[4];
#pragma unroll
    for (int ss = 0; ss < 4; ++ss) {
        f16x8 a;
        a[0] = (_Float16)xa[2 * ss].x;     a[1] = (_Float16)xa[2 * ss].y;
        a[2] = (_Float16)xa[2 * ss].z;     a[3] = (_Float16)xa[2 * ss].w;
        a[4] = (_Float16)xa[2 * ss + 1].x; a[5] = (_Float16)xa[2 * ss + 1].y;
        a[6] = (_Float16)xa[2 * ss + 1].z; a[7] = (_Float16)xa[2 * ss + 1].w;
        afrag[ss] = a;
    }

    f32x4 acc0 = {0.f, 0.f, 0.f, 0.f};
    f32x4 acc1 = {0.f, 0.f, 0.f, 0.f};
#pragma unroll
    for (int ss = 0; ss < 4; ++ss) {
        acc0 = __builtin_amdgcn_mfma_f32_16x16x32_f16(afrag[ss], bfrag[0][ss], acc0, 0, 0, 0);
        acc1 = __builtin_amdgcn_mfma_f32_16x16x32_f16(afrag[ss], bfrag[1][ss], acc1, 0, 0, 0);
    }

#pragma unroll
    for (int j = 0; j < 4; ++j) {
        int orow = r0 + kg * 4 + j;
        xwsh[(size_t)orow * DOUT + rowi]      = f2h_u(acc0[j]);
        xwsh[(size_t)orow * DOUT + 16 + rowi] = f2h_u(acc1[j]);
    }
}

// ===========================================================================
// k2: scale xwsh rows by dis = rsqrt(deg+1). Fully coalesced u32 r/m/w.
// 391 blocks x 512 threads, 256 rows per block.
// ===========================================================================
__global__ __launch_bounds__(512)
void scale_kernel(const int* __restrict__ deg, ushort_t* __restrict__ xwsh) {
    __shared__ float disL[256];
    int b = blockIdx.x, t = threadIdx.x;
    int n0 = b << 8;
    if (t < 256) {
        int n = n0 + t;
        if (n < NN) disL[t] = rsqrtf((float)(deg[n] + 1));
    }
    __syncthreads();
    for (int idx = t; idx < 256 * 16; idx += 512) {   // 16 u32 per row
        int loc = idx >> 4;
        int n = n0 + loc;
        if (n >= NN) break;
        uint_t* p = (uint_t*)(xwsh + ((size_t)n << 5)) + (idx & 15);
        uint_t v = *p;
        float dv = disL[loc];
        float lo = h2f((ushort_t)(v & 0xffffu)) * dv;
        float hi = h2f((ushort_t)(v >> 16)) * dv;
        *p = (uint_t)f2h_u(lo) | ((uint_t)f2h_u(hi) << 16);
    }
}

// ===========================================================================
// k3: FUSED sort + aggregate (per 256-node bucket).
// 1) gather this bucket's 512 chunk-segments (batched clamp-indexed loads,
//    8 in flight per thread) into LDS stage + node histogram
// 2) scan -> per-node offsets; counting-sort into stage2 (src ids)
// 3) aggregation: half-wave (32 lanes = dims) per node, 16 nodes per
//    half-wave; edge list read from LDS; xwsh gathers batched 8-deep;
//    out = dis[n]*(sum + self) + bias, written once, coalesced.
// ===========================================================================
__global__ __launch_bounds__(512)
void sortagg_kernel(const int* __restrict__ histmat,
                    const unsigned int* __restrict__ records,
                    const ushort_t* __restrict__ xwsh,
                    const float* __restrict__ bias, float* __restrict__ out) {
    __shared__ unsigned int stage[CAP];    // 32 KB
    __shared__ unsigned int stage2[CAP];   // 32 KB
    __shared__ int slen[512];
    __shared__ int hist[256];
    __shared__ int sc[256];
    __shared__ int lcur[256];
    __shared__ int off[257];
    __shared__ float disL[256];
    int b = blockIdx.x, t = threadIdx.x;

    int s_off = histmat[(size_t)t * (NBUK + 1) + b];
    int e_off = histmat[(size_t)t * (NBUK + 1) + b + 1];
    int len = e_off - s_off;
    slen[t] = len;
    if (t < 256) hist[t] = 0;
    __syncthreads();
    for (int o = 1; o < 512; o <<= 1) {
        int u = (t >= o) ? slen[t - o] : 0;
        __syncthreads();
        slen[t] += u;
        __syncthreads();
    }
    int pos = slen[t] - len;
    int cnt = slen[511];

    // batched gather of this thread's segment (8 loads in flight)
    const unsigned int* seg = records + (size_t)t * CHUNK + s_off;
    for (int k = 0; k < len; k += 8) {
        unsigned int v[8];
#pragma unroll
        for (int u = 0; u < 8; ++u) {
            int idx = k + u < len ? k + u : len - 1;   // clamp keeps loads live
            v[u] = seg[idx];
        }
#pragma unroll
        for (int u = 0; u < 8; ++u)
            if (k + u < len) {
                stage[pos + k + u] = v[u];
                atomicAdd(&hist[v[u] & 255u], 1);
            }
    }
    __syncthreads();

    int d = (t < 256) ? hist[t] : 0;
    if (t < 256) sc[t] = d;
    __syncthreads();
    for (int o = 1; o < 256; o <<= 1) {
        int u = (t < 256 && t >= o) ? sc[t - o] : 0;
        __syncthreads();
        if (t < 256) sc[t] += u;
        __syncthreads();
    }
    if (t < 256) {
        int excl = sc[t] - d;
        off[t] = excl;
        lcur[t] = excl;
        disL[t] = rsqrtf((float)(d + 1));
        if (t == 255) off[256] = cnt;
    }
    __syncthreads();
    for (int j = t; j < cnt; j += 512) {
        unsigned int rec = stage[j];
        int slot = atomicAdd(&lcur[rec & 255u], 1);
        stage2[slot] = rec >> 8;     // src row id
    }
    __syncthreads();

    // ---- aggregation: half-wave per node, 16 nodes per half-wave ----
    int hw = t >> 5;          // 0..15
    int dd = t & 31;
    int n0 = b << 8;
    float bd = bias[dd];
    for (int loc = hw; loc < 256; loc += 16) {
        int n = n0 + loc;
        if (n >= NN) break;
        int s = off[loc], e = off[loc + 1];
        float acc = h2f(xwsh[((size_t)n << 5) + dd]);   // self-loop (scaled)
        int i = s;
        for (; i + 8 <= e; i += 8) {
            int r0 = stage2[i + 0], r1 = stage2[i + 1], r2 = stage2[i + 2], r3 = stage2[i + 3];
            int r4 = stage2[i + 4], r5 = stage2[i + 5], r6 = stage2[i + 6], r7 = stage2[i + 7];
            ushort_t u0 = xwsh[((size_t)r0 << 5) + dd];
            ushort_t u1 = xwsh[((size_t)r1 << 5) + dd];
            ushort_t u2 = xwsh[((size_t)r2 << 5) + dd];
            ushort_t u3 = xwsh[((size_t)r3 << 5) + dd];
            ushort_t u4 = xwsh[((size_t)r4 << 5) + dd];
            ushort_t u5 = xwsh[((size_t)r5 << 5) + dd];
            ushort_t u6 = xwsh[((size_t)r6 << 5) + dd];
            ushort_t u7 = xwsh[((size_t)r7 << 5) + dd];
            acc += h2f(u0); acc += h2f(u1); acc += h2f(u2); acc += h2f(u3);
            acc += h2f(u4); acc += h2f(u5); acc += h2f(u6); acc += h2f(u7);
        }
        if (i + 4 <= e) {
            int r0 = stage2[i + 0], r1 = stage2[i + 1], r2 = stage2[i + 2], r3 = stage2[i + 3];
            ushort_t u0 = xwsh[((size_t)r0 << 5) + dd];
            ushort_t u1 = xwsh[((size_t)r1 << 5) + dd];
            ushort_t u2 = xwsh[((size_t)r2 << 5) + dd];
            ushort_t u3 = xwsh[((size_t)r3 << 5) + dd];
            acc += h2f(u0); acc += h2f(u1); acc += h2f(u2); acc += h2f(u3);
            i += 4;
        }
        for (; i < e; ++i) acc += h2f(xwsh[((size_t)stage2[i] << 5) + dd]);
        out[((size_t)n << 5) + dd] = disL[loc] * acc + bd;
    }
}

// ===========================================================================
// Fallback path (R1) if workspace is too small
// ===========================================================================
__global__ void deg_count_kernel(const int* __restrict__ col, int* __restrict__ deg) {
    int e = blockIdx.x * blockDim.x + threadIdx.x;
    if (e < NE) atomicAdd(&deg[col[e]], 1);
}
__global__ void dis_kernel(const int* __restrict__ deg, float* __restrict__ dis) {
    int i = blockIdx.x * blockDim.x + threadIdx.x;
    if (i < NN) dis[i] = rsqrtf((float)(deg[i] + 1));
}
__global__ void xw_init_kernel(const float* __restrict__ x, const float* __restrict__ W,
                               const float* __restrict__ b, const float* __restrict__ dis,
                               float* __restrict__ xw, float* __restrict__ out) {
    __shared__ float Ws[DIN * DOUT];
    for (int i = threadIdx.x; i < DIN * DOUT; i += blockDim.x) Ws[i] = W[i];
    __syncthreads();
    int idx = blockIdx.x * blockDim.x + threadIdx.x;
    if (idx >= NN * DOUT) return;
    int n = idx >> 5;
    int d = idx & (DOUT - 1);
    const float* xr = x + (long long)n * DIN;
    float acc = 0.f;
#pragma unroll
    for (int k = 0; k < DIN; ++k) acc += xr[k] * Ws[k * DOUT + d];
    xw[idx] = acc;
    float di = dis[n];
    out[idx] = di * di * acc + b[d];
}
__global__ void scatter_kernel(const int* __restrict__ row, const int* __restrict__ col,
                               const float* __restrict__ dis, const float* __restrict__ xw,
                               float* __restrict__ out) {
    long long idx = (long long)blockIdx.x * blockDim.x + threadIdx.x;
    if (idx >= (long long)NE * DOUT) return;
    int e = (int)(idx >> 5);
    int d = (int)(idx & (DOUT - 1));
    int r = row[e];
    int c = col[e];
    atomicAdd(&out[c * DOUT + d], dis[r] * dis[c] * xw[r * DOUT + d]);
}

// ===========================================================================
extern "C" void kernel_launch(void* const* d_in, const int* in_sizes, int n_in,
                              void* d_out, int out_size, void* d_ws, size_t ws_size,
                              hipStream_t stream) {
    const float* x  = (const float*)d_in[0];
    const int*   ei = (const int*)d_in[1];
    const float* W  = (const float*)d_in[2];
    const float* b  = (const float*)d_in[3];
    float* out = (float*)d_out;

    const int* row = ei;       // edge_index[0] = source
    const int* col = ei + NE;  // edge_index[1] = target

    char* ws = (char*)d_ws;
    int*          histmat = (int*)(ws + 0);          //   802,816 B (512*392*4)
    int*          deg     = (int*)(ws + 802816);     //   400,000 B
    unsigned int* records = (unsigned int*)(ws + 1202816);  // 6,400,000 B
    ushort_t*     xwsh    = (ushort_t*)(ws + 7602816);      // 6,400,000 B
    ushort_t*     Wht     = (ushort_t*)(ws + 14002816);     //     8,192 B
    const size_t WS_NEEDED = 14011008ull;

    if (ws_size >= WS_NEEDED) {
        wb_zero_kernel<<<8 + 196, 512, 0, stream>>>(W, Wht, deg);
        fill_xw_kernel<<<FILLB + XWB, 512, 0, stream>>>(row, col, histmat, deg,
                                                        records, x, Wht, xwsh);
        scale_kernel<<<NBUK, 512, 0, stream>>>(deg, xwsh);
        sortagg_kernel<<<NBUK, 512, 0, stream>>>(histmat, records, xwsh, b, out);
    } else {
        // fallback: atomic scatter path
        int* deg2 = (int*)(ws + 0);
        float* dis2 = (float*)(ws + 400128);
        float* xw = (float*)(ws + 800256);
        hipMemsetAsync(deg2, 0, NN * sizeof(int), stream);
        {
            int th = 256, bl = (NE + th - 1) / th;
            deg_count_kernel<<<bl, th, 0, stream>>>(col, deg2);
        }
        {
            int th = 256, bl = (NN + th - 1) / th;
            dis_kernel<<<bl, th, 0, stream>>>(deg2, dis2);
        }
        {
            long long total = (long long)NN * DOUT;
            int bl = (int)((total + 255) / 256);
            xw_init_kernel<<<bl, 256, 0, stream>>>(x, W, b, dis2, xw, out);
        }
        {
            long long total = (long long)NE * DOUT;
            int bl = (int)((total + 255) / 256);
            scatter_kernel<<<bl, 256, 0, stream>>>(row, col, dis2, xw, out);
        }
    }
}

// Round 15
// 102.385 us; speedup vs baseline: 1.4589x; 1.4589x over previous
//
#include <hip/hip_runtime.h>

#define NN 100000
#define NE 1600000
#define DIN 128
#define DOUT 32
#define NBUK 782     // ceil(NN/128) buckets of 128 nodes
#define FILLB 512    // edge chunks (512*3125 = NE exactly)
#define CHUNK 3125   // edges per chunk
#define CAP 4096     // max records per bucket staged in LDS (mean 2046, sd ~45)
#define NTILES 6250  // NN/16 MFMA row-tiles
#define XWB 391      // ceil(6250 / 16 waves)

typedef unsigned short ushort_t;
typedef unsigned int uint_t;
typedef _Float16 f16x8 __attribute__((ext_vector_type(8)));
typedef float f32x4 __attribute__((ext_vector_type(4)));

static __device__ __forceinline__ ushort_t f2h_u(float f) {
    _Float16 h = (_Float16)f;
    ushort_t u;
    __builtin_memcpy(&u, &h, 2);
    return u;
}
static __device__ __forceinline__ float h2f(ushort_t us) {
    _Float16 h;
    __builtin_memcpy(&h, &us, 2);
    return (float)h;
}

// ===========================================================================
// k0: blocks 0..7: Wht[c][k] = f16(W[k][c]); block 8: zero bsum.
// ===========================================================================
__global__ __launch_bounds__(512)
void wb_zero_kernel(const float* __restrict__ W, ushort_t* __restrict__ Wht,
                    int* __restrict__ bsum) {
    if (blockIdx.x < 8) {
        int i = blockIdx.x * 512 + threadIdx.x;   // 0..4095
        int c = i >> 7, k = i & 127;
        Wht[(size_t)c * DIN + k] = f2h_u(W[(size_t)k * DOUT + c]);
    } else {
        for (int i = threadIdx.x; i < NBUK; i += 512) bsum[i] = 0;
    }
}

// ===========================================================================
// k1: FUSED fill + xw. 1024 threads/block.
// Blocks [0, FILLB): per-chunk LDS counting sort of records by 128-node
//   bucket, then a fully COALESCED write of the chunk to records[blk*CHUNK..].
//   Chunk-local offsets -> histmat[chunk][NBUK+1]; bucket totals -> bsum.
// Blocks [FILLB, FILLB+XWB): xwsh[r] = f16(x[r] @ W) via MFMA (unscaled;
//   dis scaling happens in sort's epilogue). 16 waves * 16 rows per block.
// record = (row << 7) | (col & 127)
// ===========================================================================
__global__ __launch_bounds__(1024)
void fill_xw_kernel(const int* __restrict__ row, const int* __restrict__ col,
                    int* __restrict__ histmat, int* __restrict__ bsum,
                    unsigned int* __restrict__ records,
                    const float* __restrict__ x, const ushort_t* __restrict__ Wht,
                    ushort_t* __restrict__ xwsh) {
    __shared__ unsigned int stage[CHUNK];   // 12.5 KB
    __shared__ int hist[NBUK];              //  3.1 KB
    __shared__ int s[1024];                 //  4.0 KB
    __shared__ int lcur[NBUK];              //  3.1 KB
    if (blockIdx.x < FILLB) {
        int t = threadIdx.x, blk = blockIdx.x;
        for (int bb = t; bb < NBUK; bb += 1024) hist[bb] = 0;
        __syncthreads();
        int e0 = blk * CHUNK;
        for (int j = t; j < CHUNK; j += 1024) atomicAdd(&hist[col[e0 + j] >> 7], 1);
        __syncthreads();
        int own = (t < NBUK) ? hist[t] : 0;
        s[t] = own;
        __syncthreads();
        for (int off = 1; off < 1024; off <<= 1) {
            int u = (t >= off) ? s[t - off] : 0;
            __syncthreads();
            s[t] += u;
            __syncthreads();
        }
        int excl = s[t] - own;                 // t==NBUK -> 3125 (own=0)
        if (t <= NBUK) histmat[(size_t)blk * (NBUK + 1) + t] = excl;
        if (t < NBUK) {
            if (own) atomicAdd(&bsum[t], own);
            lcur[t] = excl;
        }
        __syncthreads();
        for (int j = t; j < CHUNK; j += 1024) {
            int e = e0 + j;
            int c = col[e];
            int slot = atomicAdd(&lcur[c >> 7], 1);
            stage[slot] = ((unsigned int)row[e] << 7) | (unsigned int)(c & 127);
        }
        __syncthreads();
        for (int j = t; j < CHUNK; j += 1024)
            records[(size_t)blk * CHUNK + j] = stage[j];
        return;
    }
    // ---- xw part: 16 waves x 16 rows ----
    int t = threadIdx.x;
    int wv = t >> 6, lane = t & 63;
    int wtile = (blockIdx.x - FILLB) * 16 + wv;
    if (wtile >= NTILES) return;           // uniform per wave
    int r0 = wtile * 16;
    int rowi = lane & 15;                  // A-row / B-col / D-col
    int kg = lane >> 4;                    // k-group (0..3)

    f16x8 bfrag[2][4];
#pragma unroll
    for (int t2 = 0; t2 < 2; ++t2)
#pragma unroll
        for (int ss = 0; ss < 4; ++ss)
            bfrag[t2][ss] = *(const f16x8*)(Wht + (size_t)(t2 * 16 + rowi) * DIN + ss * 32 + kg * 8);

    const float* __restrict__ xr = x + (size_t)(r0 + rowi) * DIN;
    float4 xa[8];
#pragma unroll
    for (int ss = 0; ss < 4; ++ss) {
        xa[2 * ss]     = *(const float4*)(xr + ss * 32 + kg * 8);
        xa[2 * ss + 1] = *(const float4*)(xr + ss * 32 + kg * 8 + 4);
    }
    f16x8 afrag[4];
#pragma unroll
    for (int ss = 0; ss < 4; ++ss) {
        f16x8 a;
        a[0] = (_Float16)xa[2 * ss].x;     a[1] = (_Float16)xa[2 * ss].y;
        a[2] = (_Float16)xa[2 * ss].z;     a[3] = (_Float16)xa[2 * ss].w;
        a[4] = (_Float16)xa[2 * ss + 1].x; a[5] = (_Float16)xa[2 * ss + 1].y;
        a[6] = (_Float16)xa[2 * ss + 1].z; a[7] = (_Float16)xa[2 * ss + 1].w;
        afrag[ss] = a;
    }

    f32x4 acc0 = {0.f, 0.f, 0.f, 0.f};
    f32x4 acc1 = {0.f, 0.f, 0.f, 0.f};
#pragma unroll
    for (int ss = 0; ss < 4; ++ss) {
        acc0 = __builtin_amdgcn_mfma_f32_16x16x32_f16(afrag[ss], bfrag[0][ss], acc0, 0, 0, 0);
        acc1 = __builtin_amdgcn_mfma_f32_16x16x32_f16(afrag[ss], bfrag[1][ss], acc1, 0, 0, 0);
    }

#pragma unroll
    for (int j = 0; j < 4; ++j) {
        int orow = r0 + kg * 4 + j;
        xwsh[(size_t)orow * DOUT + rowi]      = f2h_u(acc0[j]);
        xwsh[(size_t)orow * DOUT + 16 + rowi] = f2h_u(acc1[j]);
    }
}

// ===========================================================================
// k2: exclusive scan of NBUK bucket totals -> base[NBUK+1]. 1024 threads.
// ===========================================================================
__global__ __launch_bounds__(1024)
void bscan_kernel(const int* __restrict__ bsum, int* __restrict__ base) {
    __shared__ int s[1024];
    int t = threadIdx.x;
    int own = (t < NBUK) ? bsum[t] : 0;
    s[t] = own;
    __syncthreads();
    for (int off = 1; off < 1024; off <<= 1) {
        int v = (t >= off) ? s[t - off] : 0;
        __syncthreads();
        s[t] += v;
        __syncthreads();
    }
    if (t < NBUK) {
        base[t] = s[t] - own;
        if (t == NBUK - 1) base[NBUK] = s[t];
    }
}

// ===========================================================================
// k3: per-128-node-bucket: batched gather of the bucket's 512 chunk-segments
// (8 loads in flight per thread), LDS counting sort by node -> srcs,
// dis/offs from the histogram, xwsh-scale epilogue. 782 blocks x 512.
// ===========================================================================
__global__ __launch_bounds__(512)
void sort_kernel(const int* __restrict__ base, const int* __restrict__ histmat,
                 const unsigned int* __restrict__ records,
                 int* __restrict__ srcs, float* __restrict__ dis,
                 int* __restrict__ offs, ushort_t* __restrict__ xwsh) {
    __shared__ unsigned int stage[CAP];  // 16 KB
    __shared__ int slen[512];
    __shared__ int hist[128];
    __shared__ int sc[128];
    __shared__ int lcur[128];
    __shared__ float disL[128];
    int b = blockIdx.x, t = threadIdx.x;
    int s_off = histmat[(size_t)t * (NBUK + 1) + b];
    int e_off = histmat[(size_t)t * (NBUK + 1) + b + 1];
    int len = e_off - s_off;
    slen[t] = len;
    if (t < 128) hist[t] = 0;
    __syncthreads();
    for (int off = 1; off < 512; off <<= 1) {
        int u = (t >= off) ? slen[t - off] : 0;
        __syncthreads();
        slen[t] += u;
        __syncthreads();
    }
    int pos = slen[t] - len;
    int cnt = slen[511];

    // batched gather: 8 scattered reads in flight per thread
    const unsigned int* seg = records + (size_t)t * CHUNK + s_off;
    for (int k = 0; k < len; k += 8) {
        unsigned int v[8];
#pragma unroll
        for (int u = 0; u < 8; ++u) {
            int idx = (k + u < len) ? (k + u) : (len - 1);
            v[u] = seg[idx];
        }
#pragma unroll
        for (int u = 0; u < 8; ++u)
            if (k + u < len) {
                stage[pos + k + u] = v[u];
                atomicAdd(&hist[v[u] & 127u], 1);
            }
    }
    __syncthreads();

    int d = (t < 128) ? hist[t] : 0;
    if (t < 128) sc[t] = d;
    __syncthreads();
    for (int off = 1; off < 128; off <<= 1) {
        int u = (t < 128 && t >= off) ? sc[t - off] : 0;
        __syncthreads();
        if (t < 128) sc[t] += u;
        __syncthreads();
    }
    int sbase = base[b];
    if (t < 128) {
        int excl = sc[t] - d;
        float dv = rsqrtf((float)(d + 1));
        disL[t] = dv;
        int n = (b << 7) + t;
        if (n < NN) {
            dis[n] = dv;
            offs[n] = sbase + excl;
            if (n == NN - 1) offs[NN] = sbase + cnt;
        }
        lcur[t] = excl;
    }
    __syncthreads();
    for (int j = t; j < cnt; j += 512) {
        unsigned int rec = stage[j];
        int slot = atomicAdd(&lcur[rec & 127u], 1);
        srcs[sbase + slot] = (int)(rec >> 7);
    }
    // epilogue: scale this bucket's 128 xwsh rows by dis (coalesced u32 r/m/w)
    int n0 = b << 7;
    for (int idx = t; idx < 128 * 16; idx += 512) {
        int loc = idx >> 4;
        int n = n0 + loc;
        if (n >= NN) break;
        uint_t* p = (uint_t*)(xwsh + ((size_t)n << 5)) + (idx & 15);
        uint_t v = *p;
        float dv = disL[loc];
        float lo = h2f((ushort_t)(v & 0xffffu)) * dv;
        float hi = h2f((ushort_t)(v >> 16)) * dv;
        *p = (uint_t)f2h_u(lo) | ((uint_t)f2h_u(hi) << 16);
    }
}

// ===========================================================================
// k4: aggregate, zero-reduce layout. Half-wave (32 lanes) = one node; lane
// owns one output dim and serially walks the node's edge list. Per edge the
// 32 lanes read one coalesced 64B row (u16/lane); f32 accumulate; unroll 8.
// ===========================================================================
__global__ __launch_bounds__(256)
void aggregate_kernel(const int* __restrict__ offs, const int* __restrict__ srcs,
                      const float* __restrict__ dis, const ushort_t* __restrict__ xwsh,
                      const float* __restrict__ bias, float* __restrict__ out) {
    int gw = (int)((blockIdx.x * (long long)blockDim.x + threadIdx.x) >> 6);
    int half = (threadIdx.x >> 5) & 1;
    int wid = gw * 2 + half;
    if (wid >= NN) return;
    int d = threadIdx.x & 31;

    int s = offs[wid], e = offs[wid + 1];
    float acc = h2f(xwsh[((size_t)wid << 5) + d]);   // self-loop (scaled)
    int i = s;
    for (; i + 8 <= e; i += 8) {
        int r0 = srcs[i + 0], r1 = srcs[i + 1], r2 = srcs[i + 2], r3 = srcs[i + 3];
        int r4 = srcs[i + 4], r5 = srcs[i + 5], r6 = srcs[i + 6], r7 = srcs[i + 7];
        ushort_t u0 = xwsh[((size_t)r0 << 5) + d];
        ushort_t u1 = xwsh[((size_t)r1 << 5) + d];
        ushort_t u2 = xwsh[((size_t)r2 << 5) + d];
        ushort_t u3 = xwsh[((size_t)r3 << 5) + d];
        ushort_t u4 = xwsh[((size_t)r4 << 5) + d];
        ushort_t u5 = xwsh[((size_t)r5 << 5) + d];
        ushort_t u6 = xwsh[((size_t)r6 << 5) + d];
        ushort_t u7 = xwsh[((size_t)r7 << 5) + d];
        acc += h2f(u0); acc += h2f(u1); acc += h2f(u2); acc += h2f(u3);
        acc += h2f(u4); acc += h2f(u5); acc += h2f(u6); acc += h2f(u7);
    }
    if (i + 4 <= e) {
        int r0 = srcs[i + 0], r1 = srcs[i + 1], r2 = srcs[i + 2], r3 = srcs[i + 3];
        ushort_t u0 = xwsh[((size_t)r0 << 5) + d];
        ushort_t u1 = xwsh[((size_t)r1 << 5) + d];
        ushort_t u2 = xwsh[((size_t)r2 << 5) + d];
        ushort_t u3 = xwsh[((size_t)r3 << 5) + d];
        acc += h2f(u0); acc += h2f(u1); acc += h2f(u2); acc += h2f(u3);
        i += 4;
    }
    for (; i < e; ++i) acc += h2f(xwsh[((size_t)srcs[i] << 5) + d]);

    out[((size_t)wid << 5) + d] = dis[wid] * acc + bias[d];
}

// ===========================================================================
// Fallback path (R1) if workspace is too small
// ===========================================================================
__global__ void deg_count_kernel(const int* __restrict__ col, int* __restrict__ deg) {
    int e = blockIdx.x * blockDim.x + threadIdx.x;
    if (e < NE) atomicAdd(&deg[col[e]], 1);
}
__global__ void dis_kernel(const int* __restrict__ deg, float* __restrict__ dis) {
    int i = blockIdx.x * blockDim.x + threadIdx.x;
    if (i < NN) dis[i] = rsqrtf((float)(deg[i] + 1));
}
__global__ void xw_init_kernel(const float* __restrict__ x, const float* __restrict__ W,
                               const float* __restrict__ b, const float* __restrict__ dis,
                               float* __restrict__ xw, float* __restrict__ out) {
    __shared__ float Ws[DIN * DOUT];
    for (int i = threadIdx.x; i < DIN * DOUT; i += blockDim.x) Ws[i] = W[i];
    __syncthreads();
    int idx = blockIdx.x * blockDim.x + threadIdx.x;
    if (idx >= NN * DOUT) return;
    int n = idx >> 5;
    int d = idx & (DOUT - 1);
    const float* xr = x + (long long)n * DIN;
    float acc = 0.f;
#pragma unroll
    for (int k = 0; k < DIN; ++k) acc += xr[k] * Ws[k * DOUT + d];
    xw[idx] = acc;
    float di = dis[n];
    out[idx] = di * di * acc + b[d];
}
__global__ void scatter_kernel(const int* __restrict__ row, const int* __restrict__ col,
                               const float* __restrict__ dis, const float* __restrict__ xw,
                               float* __restrict__ out) {
    long long idx = (long long)blockIdx.x * blockDim.x + threadIdx.x;
    if (idx >= (long long)NE * DOUT) return;
    int e = (int)(idx >> 5);
    int d = (int)(idx & (DOUT - 1));
    int r = row[e];
    int c = col[e];
    atomicAdd(&out[c * DOUT + d], dis[r] * dis[c] * xw[r * DOUT + d]);
}

// ===========================================================================
extern "C" void kernel_launch(void* const* d_in, const int* in_sizes, int n_in,
                              void* d_out, int out_size, void* d_ws, size_t ws_size,
                              hipStream_t stream) {
    const float* x  = (const float*)d_in[0];
    const int*   ei = (const int*)d_in[1];
    const float* W  = (const float*)d_in[2];
    const float* b  = (const float*)d_in[3];
    float* out = (float*)d_out;

    const int* row = ei;       // edge_index[0] = source
    const int* col = ei + NE;  // edge_index[1] = target

    char* ws = (char*)d_ws;
    int*          histmat = (int*)(ws + 0);          // 512*783*4 = 1,603,584 B
    int*          bsum    = (int*)(ws + 1603584);    //     3,128 B
    int*          base    = (int*)(ws + 1606784);    //     3,132 B
    int*          offs    = (int*)(ws + 1610112);    //   400,004 B
    float*        dis     = (float*)(ws + 2010240);  //   400,000 B
    unsigned int* records = (unsigned int*)(ws + 2410368);  // 6,400,000 B
    int*          srcs    = (int*)(ws + 8810368);    // 6,400,000 B
    ushort_t*     xwsh    = (ushort_t*)(ws + 15210368);     // 6,400,000 B
    ushort_t*     Wht     = (ushort_t*)(ws + 21610368);     //     8,192 B
    const size_t WS_NEEDED = 21618560ull;

    if (ws_size >= WS_NEEDED) {
        wb_zero_kernel<<<9, 512, 0, stream>>>(W, Wht, bsum);
        fill_xw_kernel<<<FILLB + XWB, 1024, 0, stream>>>(row, col, histmat, bsum,
                                                         records, x, Wht, xwsh);
        bscan_kernel<<<1, 1024, 0, stream>>>(bsum, base);
        sort_kernel<<<NBUK, 512, 0, stream>>>(base, histmat, records, srcs, dis, offs, xwsh);
        {
            long long waves = (NN + 1) / 2;             // 2 nodes per wave
            int bl = (int)((waves + 3) / 4);            // 4 waves per block
            aggregate_kernel<<<bl, 256, 0, stream>>>(offs, srcs, dis, xwsh, b, out);
        }
    } else {
        // fallback: atomic scatter path
        int* deg2 = (int*)(ws + 0);
        float* dis2 = (float*)(ws + 400128);
        float* xw = (float*)(ws + 800256);
        hipMemsetAsync(deg2, 0, NN * sizeof(int), stream);
        {
            int th = 256, bl = (NE + th - 1) / th;
            deg_count_kernel<<<bl, th, 0, stream>>>(col, deg2);
        }
        {
            int th = 256, bl = (NN + th - 1) / th;
            dis_kernel<<<bl, th, 0, stream>>>(deg2, dis2);
        }
        {
            long long total = (long long)NN * DOUT;
            int bl = (int)((total + 255) / 256);
            xw_init_kernel<<<bl, 256, 0, stream>>>(x, W, b, dis2, xw, out);
        }
        {
            long long total = (long long)NE * DOUT;
            int bl = (int)((total + 255) / 256);
            scatter_kernel<<<bl, 256, 0, stream>>>(row, col, dis2, xw, out);
        }
    }
}

// Round 16
// 90.442 us; speedup vs baseline: 1.6515x; 1.1321x over previous
//
#include <hip/hip_runtime.h>

#define NN 100000
#define NE 1600000
#define DIN 128
#define DOUT 32
#define NBUK 391     // ceil(NN/256) buckets of 256 nodes
#define FILLB 512    // edge chunks (512*3125 = NE exactly)
#define CHUNK 3125   // edges per chunk
#define CAP 8192     // max records per bucket staged in LDS (mean 4092, sd ~64)
#define NTILES 6250  // NN/16 MFMA row-tiles
#define XWB 782      // ceil(6250 / 8 waves)

typedef unsigned short ushort_t;
typedef unsigned int uint_t;
typedef _Float16 f16x8 __attribute__((ext_vector_type(8)));
typedef float f32x4 __attribute__((ext_vector_type(4)));

static __device__ __forceinline__ ushort_t f2h_u(float f) {
    _Float16 h = (_Float16)f;
    ushort_t u;
    __builtin_memcpy(&u, &h, 2);
    return u;
}
static __device__ __forceinline__ float h2f(ushort_t us) {
    _Float16 h;
    __builtin_memcpy(&h, &us, 2);
    return (float)h;
}

// ===========================================================================
// k0: blocks 0..7: Wht[c][k] = f16(W[k][c]); block 8: zero bsum.
// ===========================================================================
__global__ __launch_bounds__(512)
void wb_zero_kernel(const float* __restrict__ W, ushort_t* __restrict__ Wht,
                    int* __restrict__ bsum) {
    if (blockIdx.x < 8) {
        int i = blockIdx.x * 512 + threadIdx.x;   // 0..4095
        int c = i >> 7, k = i & 127;
        Wht[(size_t)c * DIN + k] = f2h_u(W[(size_t)k * DOUT + c]);
    } else {
        int t = threadIdx.x;
        if (t < NBUK) bsum[t] = 0;
    }
}

// ===========================================================================
// k1: FUSED fill + xw (R13-proven config: 512 threads, 256-node buckets).
// Blocks [0, FILLB): per-chunk LDS counting sort by bucket + COALESCED
//   write of the chunk to records[blk*CHUNK..]; chunk offsets -> histmat;
//   bucket totals -> bsum.
// Blocks [FILLB, FILLB+XWB): xwsh[r] = f16(x[r] @ W) via MFMA (unscaled).
// record = (row << 8) | (col & 255)
// ===========================================================================
__global__ __launch_bounds__(512)
void fill_xw_kernel(const int* __restrict__ row, const int* __restrict__ col,
                    int* __restrict__ histmat, int* __restrict__ bsum,
                    unsigned int* __restrict__ records,
                    const float* __restrict__ x, const ushort_t* __restrict__ Wht,
                    ushort_t* __restrict__ xwsh) {
    __shared__ unsigned int stage[CHUNK];   // 12.5 KB
    __shared__ int hist[NBUK];
    __shared__ int s[512];
    __shared__ int lcur[NBUK];
    if (blockIdx.x < FILLB) {
        int t = threadIdx.x, blk = blockIdx.x;
        for (int bb = t; bb < NBUK; bb += 512) hist[bb] = 0;
        __syncthreads();
        int e0 = blk * CHUNK;
        for (int j = t; j < CHUNK; j += 512) atomicAdd(&hist[col[e0 + j] >> 8], 1);
        __syncthreads();
        int own = (t < NBUK) ? hist[t] : 0;
        s[t] = own;
        __syncthreads();
        for (int off = 1; off < 512; off <<= 1) {
            int u = (t >= off) ? s[t - off] : 0;
            __syncthreads();
            s[t] += u;
            __syncthreads();
        }
        int excl = s[t] - own;                 // t==NBUK -> 3125 (own=0)
        if (t <= NBUK) histmat[(size_t)blk * (NBUK + 1) + t] = excl;
        if (t < NBUK) {
            if (own) atomicAdd(&bsum[t], own);
            lcur[t] = excl;
        }
        __syncthreads();
        for (int j = t; j < CHUNK; j += 512) {
            int e = e0 + j;
            int c = col[e];
            int slot = atomicAdd(&lcur[c >> 8], 1);
            stage[slot] = ((unsigned int)row[e] << 8) | (unsigned int)(c & 255);
        }
        __syncthreads();
        for (int j = t; j < CHUNK; j += 512)
            records[(size_t)blk * CHUNK + j] = stage[j];
        return;
    }
    // ---- xw part: 8 waves x 16 rows ----
    int t = threadIdx.x;
    int wv = t >> 6, lane = t & 63;
    int wtile = (blockIdx.x - FILLB) * 8 + wv;
    if (wtile >= NTILES) return;           // uniform per wave
    int r0 = wtile * 16;
    int rowi = lane & 15;                  // A-row / B-col / D-col
    int kg = lane >> 4;                    // k-group (0..3)

    f16x8 bfrag[2][4];
#pragma unroll
    for (int t2 = 0; t2 < 2; ++t2)
#pragma unroll
        for (int ss = 0; ss < 4; ++ss)
            bfrag[t2][ss] = *(const f16x8*)(Wht + (size_t)(t2 * 16 + rowi) * DIN + ss * 32 + kg * 8);

    const float* __restrict__ xr = x + (size_t)(r0 + rowi) * DIN;
    float4 xa[8];
#pragma unroll
    for (int ss = 0; ss < 4; ++ss) {
        xa[2 * ss]     = *(const float4*)(xr + ss * 32 + kg * 8);
        xa[2 * ss + 1] = *(const float4*)(xr + ss * 32 + kg * 8 + 4);
    }
    f16x8 afrag[4];
#pragma unroll
    for (int ss = 0; ss < 4; ++ss) {
        f16x8 a;
        a[0] = (_Float16)xa[2 * ss].x;     a[1] = (_Float16)xa[2 * ss].y;
        a[2] = (_Float16)xa[2 * ss].z;     a[3] = (_Float16)xa[2 * ss].w;
        a[4] = (_Float16)xa[2 * ss + 1].x; a[5] = (_Float16)xa[2 * ss + 1].y;
        a[6] = (_Float16)xa[2 * ss + 1].z; a[7] = (_Float16)xa[2 * ss + 1].w;
        afrag[ss] = a;
    }

    f32x4 acc0 = {0.f, 0.f, 0.f, 0.f};
    f32x4 acc1 = {0.f, 0.f, 0.f, 0.f};
#pragma unroll
    for (int ss = 0; ss < 4; ++ss) {
        acc0 = __builtin_amdgcn_mfma_f32_16x16x32_f16(afrag[ss], bfrag[0][ss], acc0, 0, 0, 0);
        acc1 = __builtin_amdgcn_mfma_f32_16x16x32_f16(afrag[ss], bfrag[1][ss], acc1, 0, 0, 0);
    }

#pragma unroll
    for (int j = 0; j < 4; ++j) {
        int orow = r0 + kg * 4 + j;
        xwsh[(size_t)orow * DOUT + rowi]      = f2h_u(acc0[j]);
        xwsh[(size_t)orow * DOUT + 16 + rowi] = f2h_u(acc1[j]);
    }
}

// ===========================================================================
// k2: exclusive scan of bucket totals -> base[NBUK+1]
// ===========================================================================
__global__ __launch_bounds__(512)
void bscan_kernel(const int* __restrict__ bsum, int* __restrict__ base) {
    __shared__ int s[512];
    int t = threadIdx.x;
    int own = (t < NBUK) ? bsum[t] : 0;
    s[t] = own;
    __syncthreads();
    for (int off = 1; off < 512; off <<= 1) {
        int v = (t >= off) ? s[t - off] : 0;
        __syncthreads();
        s[t] += v;
        __syncthreads();
    }
    if (t < NBUK) {
        base[t] = s[t] - own;
        if (t == NBUK - 1) base[NBUK] = s[t];
    }
}

// ===========================================================================
// k3: per-bucket: clamp-batched gather of the bucket's 512 chunk-segments
// (8 scattered reads in flight per thread), LDS counting sort by node ->
// srcs, dis/offs from the histogram, xwsh-scale epilogue. 391 blocks x 512.
// ===========================================================================
__global__ __launch_bounds__(512)
void sort_kernel(const int* __restrict__ base, const int* __restrict__ histmat,
                 const unsigned int* __restrict__ records,
                 int* __restrict__ srcs, float* __restrict__ dis,
                 int* __restrict__ offs, ushort_t* __restrict__ xwsh) {
    __shared__ unsigned int stage[CAP];  // 32 KB
    __shared__ int slen[512];
    __shared__ int hist[256];
    __shared__ int sc[256];
    __shared__ int lcur[256];
    __shared__ float disL[256];
    int b = blockIdx.x, t = threadIdx.x;
    int s_off = histmat[(size_t)t * (NBUK + 1) + b];
    int e_off = histmat[(size_t)t * (NBUK + 1) + b + 1];
    int len = e_off - s_off;
    slen[t] = len;
    if (t < 256) hist[t] = 0;
    __syncthreads();
    for (int off = 1; off < 512; off <<= 1) {
        int u = (t >= off) ? slen[t - off] : 0;
        __syncthreads();
        slen[t] += u;
        __syncthreads();
    }
    int pos = slen[t] - len;
    int cnt = slen[511];

    // clamp-batched gather: 8 scattered reads in flight per thread
    const unsigned int* seg = records + (size_t)t * CHUNK + s_off;
    for (int k = 0; k < len; k += 8) {
        unsigned int v[8];
#pragma unroll
        for (int u = 0; u < 8; ++u) {
            int idx = (k + u < len) ? (k + u) : (len - 1);
            v[u] = seg[idx];
        }
#pragma unroll
        for (int u = 0; u < 8; ++u)
            if (k + u < len) {
                stage[pos + k + u] = v[u];
                atomicAdd(&hist[v[u] & 255u], 1);
            }
    }
    __syncthreads();

    int d = (t < 256) ? hist[t] : 0;
    if (t < 256) sc[t] = d;
    __syncthreads();
    for (int off = 1; off < 256; off <<= 1) {
        int u = (t < 256 && t >= off) ? sc[t - off] : 0;
        __syncthreads();
        if (t < 256) sc[t] += u;
        __syncthreads();
    }
    int sbase = base[b];
    if (t < 256) {
        int excl = sc[t] - d;
        float dv = rsqrtf((float)(d + 1));
        disL[t] = dv;
        int n = (b << 8) + t;
        if (n < NN) {
            dis[n] = dv;
            offs[n] = sbase + excl;
            if (n == NN - 1) offs[NN] = sbase + cnt;
        }
        lcur[t] = excl;
    }
    __syncthreads();
    for (int j = t; j < cnt; j += 512) {
        unsigned int rec = stage[j];
        int slot = atomicAdd(&lcur[rec & 255u], 1);
        srcs[sbase + slot] = (int)(rec >> 8);
    }
    // epilogue: scale this bucket's xwsh rows by dis (coalesced u32 r/m/w)
    int n0 = b << 8;
    for (int idx = t; idx < 256 * 16; idx += 512) {
        int loc = idx >> 4;
        int n = n0 + loc;
        if (n >= NN) break;
        uint_t* p = (uint_t*)(xwsh + ((size_t)n << 5)) + (idx & 15);
        uint_t v = *p;
        float dv = disL[loc];
        float lo = h2f((ushort_t)(v & 0xffffu)) * dv;
        float hi = h2f((ushort_t)(v >> 16)) * dv;
        *p = (uint_t)f2h_u(lo) | ((uint_t)f2h_u(hi) << 16);
    }
}

// ===========================================================================
// k4: aggregate, zero-reduce layout, FULLY BATCHED (no serial remainder).
// Half-wave (32 lanes) = one node; lane owns one output dim. Every 8-edge
// round issues 8 independent srcs reads (contiguous) + 8 independent xwsh
// gathers; tail lanes clamp to e-1 and mask the accumulate.
// ===========================================================================
__global__ __launch_bounds__(256)
void aggregate_kernel(const int* __restrict__ offs, const int* __restrict__ srcs,
                      const float* __restrict__ dis, const ushort_t* __restrict__ xwsh,
                      const float* __restrict__ bias, float* __restrict__ out) {
    int gw = (int)((blockIdx.x * (long long)blockDim.x + threadIdx.x) >> 6);
    int half = (threadIdx.x >> 5) & 1;
    int wid = gw * 2 + half;
    if (wid >= NN) return;
    int d = threadIdx.x & 31;

    int s = offs[wid], e = offs[wid + 1];
    float acc = h2f(xwsh[((size_t)wid << 5) + d]);   // self-loop (scaled)
    for (int i = s; i < e; i += 8) {
        int r[8];
        ushort_t u[8];
#pragma unroll
        for (int k = 0; k < 8; ++k) {
            int j = i + k;
            r[k] = srcs[j < e ? j : e - 1];
        }
#pragma unroll
        for (int k = 0; k < 8; ++k) u[k] = xwsh[((size_t)r[k] << 5) + d];
#pragma unroll
        for (int k = 0; k < 8; ++k) acc += (i + k < e) ? h2f(u[k]) : 0.f;
    }
    out[((size_t)wid << 5) + d] = dis[wid] * acc + bias[d];
}

// ===========================================================================
// Fallback path (R1) if workspace is too small
// ===========================================================================
__global__ void deg_count_kernel(const int* __restrict__ col, int* __restrict__ deg) {
    int e = blockIdx.x * blockDim.x + threadIdx.x;
    if (e < NE) atomicAdd(&deg[col[e]], 1);
}
__global__ void dis_kernel(const int* __restrict__ deg, float* __restrict__ dis) {
    int i = blockIdx.x * blockDim.x + threadIdx.x;
    if (i < NN) dis[i] = rsqrtf((float)(deg[i] + 1));
}
__global__ void xw_init_kernel(const float* __restrict__ x, const float* __restrict__ W,
                               const float* __restrict__ b, const float* __restrict__ dis,
                               float* __restrict__ xw, float* __restrict__ out) {
    __shared__ float Ws[DIN * DOUT];
    for (int i = threadIdx.x; i < DIN * DOUT; i += blockDim.x) Ws[i] = W[i];
    __syncthreads();
    int idx = blockIdx.x * blockDim.x + threadIdx.x;
    if (idx >= NN * DOUT) return;
    int n = idx >> 5;
    int d = idx & (DOUT - 1);
    const float* xr = x + (long long)n * DIN;
    float acc = 0.f;
#pragma unroll
    for (int k = 0; k < DIN; ++k) acc += xr[k] * Ws[k * DOUT + d];
    xw[idx] = acc;
    float di = dis[n];
    out[idx] = di * di * acc + b[d];
}
__global__ void scatter_kernel(const int* __restrict__ row, const int* __restrict__ col,
                               const float* __restrict__ dis, const float* __restrict__ xw,
                               float* __restrict__ out) {
    long long idx = (long long)blockIdx.x * blockDim.x + threadIdx.x;
    if (idx >= (long long)NE * DOUT) return;
    int e = (int)(idx >> 5);
    int d = (int)(idx & (DOUT - 1));
    int r = row[e];
    int c = col[e];
    atomicAdd(&out[c * DOUT + d], dis[r] * dis[c] * xw[r * DOUT + d]);
}

// ===========================================================================
extern "C" void kernel_launch(void* const* d_in, const int* in_sizes, int n_in,
                              void* d_out, int out_size, void* d_ws, size_t ws_size,
                              hipStream_t stream) {
    const float* x  = (const float*)d_in[0];
    const int*   ei = (const int*)d_in[1];
    const float* W  = (const float*)d_in[2];
    const float* b  = (const float*)d_in[3];
    float* out = (float*)d_out;

    const int* row = ei;       // edge_index[0] = source
    const int* col = ei + NE;  // edge_index[1] = target

    char* ws = (char*)d_ws;
    int*          histmat = (int*)(ws + 0);          //   802,816 B (512*392*4)
    int*          bsum    = (int*)(ws + 802816);     //     1,564 B
    int*          base    = (int*)(ws + 804480);     //     1,568 B (NBUK+1)
    int*          offs    = (int*)(ws + 806144);     //   400,004 B (NN+1)
    float*        dis     = (float*)(ws + 1206272);  //   400,000 B
    unsigned int* records = (unsigned int*)(ws + 1606272);  // 6,400,000 B
    int*          srcs    = (int*)(ws + 8006272);    // 6,400,000 B
    ushort_t*     xwsh    = (ushort_t*)(ws + 14406272);     // 6,400,000 B
    ushort_t*     Wht     = (ushort_t*)(ws + 20806272);     //     8,192 B
    const size_t WS_NEEDED = 20814464ull;

    if (ws_size >= WS_NEEDED) {
        wb_zero_kernel<<<9, 512, 0, stream>>>(W, Wht, bsum);
        fill_xw_kernel<<<FILLB + XWB, 512, 0, stream>>>(row, col, histmat, bsum,
                                                        records, x, Wht, xwsh);
        bscan_kernel<<<1, 512, 0, stream>>>(bsum, base);
        sort_kernel<<<NBUK, 512, 0, stream>>>(base, histmat, records, srcs, dis, offs, xwsh);
        {
            long long waves = (NN + 1) / 2;             // 2 nodes per wave
            int bl = (int)((waves + 3) / 4);            // 4 waves per block
            aggregate_kernel<<<bl, 256, 0, stream>>>(offs, srcs, dis, xwsh, b, out);
        }
    } else {
        // fallback: atomic scatter path
        int* deg2 = (int*)(ws + 0);
        float* dis2 = (float*)(ws + 400128);
        float* xw = (float*)(ws + 800256);
        hipMemsetAsync(deg2, 0, NN * sizeof(int), stream);
        {
            int th = 256, bl = (NE + th - 1) / th;
            deg_count_kernel<<<bl, th, 0, stream>>>(col, deg2);
        }
        {
            int th = 256, bl = (NN + th - 1) / th;
            dis_kernel<<<bl, th, 0, stream>>>(deg2, dis2);
        }
        {
            long long total = (long long)NN * DOUT;
            int bl = (int)((total + 255) / 256);
            xw_init_kernel<<<bl, 256, 0, stream>>>(x, W, b, dis2, xw, out);
        }
        {
            long long total = (long long)NE * DOUT;
            int bl = (int)((total + 255) / 256);
            scatter_kernel<<<bl, 256, 0, stream>>>(row, col, dis2, xw, out);
        }
    }
}

// Round 17
// 76.046 us; speedup vs baseline: 1.9641x; 1.1893x over previous
//
#include <hip/hip_runtime.h>

#define NN 100000
#define NE 1600000
#define DIN 128
#define DOUT 32
#define NBUK 391     // ceil(NN/256) buckets of 256 nodes
#define FILLB 512    // edge chunks (512*3125 = NE exactly)
#define CHUNK 3125   // edges per chunk
#define CAP 8192     // LDS stage capacity per bucket (counts mean 4092, sd 64)
#define CAP_PAD 4608 // padded per-bucket srcs region (mean + 8 sd)
#define NTILES 6250  // NN/16 MFMA row-tiles
#define XWB 782      // ceil(6250 / 8 waves)

typedef unsigned short ushort_t;
typedef unsigned int uint_t;
typedef _Float16 f16x8 __attribute__((ext_vector_type(8)));
typedef float f32x4 __attribute__((ext_vector_type(4)));

static __device__ __forceinline__ ushort_t f2h_u(float f) {
    _Float16 h = (_Float16)f;
    ushort_t u;
    __builtin_memcpy(&u, &h, 2);
    return u;
}
static __device__ __forceinline__ float h2f(ushort_t us) {
    _Float16 h;
    __builtin_memcpy(&h, &us, 2);
    return (float)h;
}

// ===========================================================================
// k1: FUSED fill + xw.
// Blocks [0, FILLB): histogram (col staged to LDS) -> scan -> LDS counting
//   sort -> COALESCED records write; chunk-local offsets -> histmat.
// Blocks [FILLB, FILLB+XWB): xwsh[r] = f16(x[r] @ W) via MFMA, B-fragments
//   loaded directly from global W (L1-resident) with f32->f16 convert.
// record = (row << 8) | (col & 255)
// ===========================================================================
__global__ __launch_bounds__(512)
void fill_xw_kernel(const int* __restrict__ row, const int* __restrict__ col,
                    int* __restrict__ histmat, unsigned int* __restrict__ records,
                    const float* __restrict__ x, const float* __restrict__ W,
                    ushort_t* __restrict__ xwsh) {
    __shared__ unsigned int stage[CHUNK];    // 12.5 KB
    __shared__ int colstage[CHUNK];          // 12.5 KB
    __shared__ int hist[NBUK];
    __shared__ int s[512];
    __shared__ int lcur[NBUK];
    if (blockIdx.x < FILLB) {
        int t = threadIdx.x, blk = blockIdx.x;
        for (int bb = t; bb < NBUK; bb += 512) hist[bb] = 0;
        __syncthreads();
        int e0 = blk * CHUNK;
        for (int j = t; j < CHUNK; j += 512) {
            int c = col[e0 + j];
            colstage[j] = c;
            atomicAdd(&hist[c >> 8], 1);
        }
        __syncthreads();
        int own = (t < NBUK) ? hist[t] : 0;
        s[t] = own;
        __syncthreads();
        for (int off = 1; off < 512; off <<= 1) {
            int u = (t >= off) ? s[t - off] : 0;
            __syncthreads();
            s[t] += u;
            __syncthreads();
        }
        int excl = s[t] - own;                 // t==NBUK -> 3125 (own=0)
        if (t <= NBUK) histmat[(size_t)blk * (NBUK + 1) + t] = excl;
        if (t < NBUK) lcur[t] = excl;
        __syncthreads();
        for (int j = t; j < CHUNK; j += 512) {
            int c = colstage[j];
            int slot = atomicAdd(&lcur[c >> 8], 1);
            stage[slot] = ((unsigned int)row[e0 + j] << 8) | (unsigned int)(c & 255);
        }
        __syncthreads();
        for (int j = t; j < CHUNK; j += 512)
            records[(size_t)blk * CHUNK + j] = stage[j];
        return;
    }
    // ---- xw part: 8 waves x 16 rows ----
    int t = threadIdx.x;
    int wv = t >> 6, lane = t & 63;
    int wtile = (blockIdx.x - FILLB) * 8 + wv;
    if (wtile >= NTILES) return;           // uniform per wave
    int r0 = wtile * 16;
    int rowi = lane & 15;                  // A-row / B-col / D-col
    int kg = lane >> 4;                    // k-group (0..3)

    // B fragments straight from W (16 KB, L1-resident): W[k][c], k-run of 8
    f16x8 bfrag[2][4];
#pragma unroll
    for (int t2 = 0; t2 < 2; ++t2) {
        int c = t2 * 16 + rowi;
#pragma unroll
        for (int ss = 0; ss < 4; ++ss) {
            const float* Wp = W + (size_t)(ss * 32 + kg * 8) * DOUT + c;
            f16x8 bf;
#pragma unroll
            for (int i = 0; i < 8; ++i) bf[i] = (_Float16)Wp[i * DOUT];
            bfrag[t2][ss] = bf;
        }
    }

    const float* __restrict__ xr = x + (size_t)(r0 + rowi) * DIN;
    float4 xa[8];
#pragma unroll
    for (int ss = 0; ss < 4; ++ss) {
        xa[2 * ss]     = *(const float4*)(xr + ss * 32 + kg * 8);
        xa[2 * ss + 1] = *(const float4*)(xr + ss * 32 + kg * 8 + 4);
    }
    f16x8 afrag[4];
#pragma unroll
    for (int ss = 0; ss < 4; ++ss) {
        f16x8 a;
        a[0] = (_Float16)xa[2 * ss].x;     a[1] = (_Float16)xa[2 * ss].y;
        a[2] = (_Float16)xa[2 * ss].z;     a[3] = (_Float16)xa[2 * ss].w;
        a[4] = (_Float16)xa[2 * ss + 1].x; a[5] = (_Float16)xa[2 * ss + 1].y;
        a[6] = (_Float16)xa[2 * ss + 1].z; a[7] = (_Float16)xa[2 * ss + 1].w;
        afrag[ss] = a;
    }

    f32x4 acc0 = {0.f, 0.f, 0.f, 0.f};
    f32x4 acc1 = {0.f, 0.f, 0.f, 0.f};
#pragma unroll
    for (int ss = 0; ss < 4; ++ss) {
        acc0 = __builtin_amdgcn_mfma_f32_16x16x32_f16(afrag[ss], bfrag[0][ss], acc0, 0, 0, 0);
        acc1 = __builtin_amdgcn_mfma_f32_16x16x32_f16(afrag[ss], bfrag[1][ss], acc1, 0, 0, 0);
    }

#pragma unroll
    for (int j = 0; j < 4; ++j) {
        int orow = r0 + kg * 4 + j;
        xwsh[(size_t)orow * DOUT + rowi]      = f2h_u(acc0[j]);
        xwsh[(size_t)orow * DOUT + 16 + rowi] = f2h_u(acc1[j]);
    }
}

// ===========================================================================
// k2: per-bucket sort. No global prefix needed: bucket b owns the fixed
// region srcs[b*CAP_PAD ...]. Clamp-batched segment gather (8 reads in
// flight), LDS counting sort by node, per-node offs/ends/dis, xwsh-scale
// epilogue. 391 blocks x 512.
// ===========================================================================
__global__ __launch_bounds__(512)
void sort_kernel(const int* __restrict__ histmat,
                 const unsigned int* __restrict__ records,
                 int* __restrict__ srcs, float* __restrict__ dis,
                 int* __restrict__ offs, int* __restrict__ ends,
                 ushort_t* __restrict__ xwsh) {
    __shared__ unsigned int stage[CAP];  // 32 KB
    __shared__ int slen[512];
    __shared__ int hist[256];
    __shared__ int sc[256];
    __shared__ int lcur[256];
    __shared__ float disL[256];
    int b = blockIdx.x, t = threadIdx.x;
    int s_off = histmat[(size_t)t * (NBUK + 1) + b];
    int e_off = histmat[(size_t)t * (NBUK + 1) + b + 1];
    int len = e_off - s_off;
    slen[t] = len;
    if (t < 256) hist[t] = 0;
    __syncthreads();
    for (int off = 1; off < 512; off <<= 1) {
        int u = (t >= off) ? slen[t - off] : 0;
        __syncthreads();
        slen[t] += u;
        __syncthreads();
    }
    int pos = slen[t] - len;
    int cnt = slen[511];

    // clamp-batched gather: 8 scattered reads in flight per thread
    const unsigned int* seg = records + (size_t)t * CHUNK + s_off;
    for (int k = 0; k < len; k += 8) {
        unsigned int v[8];
#pragma unroll
        for (int u = 0; u < 8; ++u) {
            int idx = (k + u < len) ? (k + u) : (len - 1);
            v[u] = seg[idx];
        }
#pragma unroll
        for (int u = 0; u < 8; ++u)
            if (k + u < len) {
                stage[pos + k + u] = v[u];
                atomicAdd(&hist[v[u] & 255u], 1);
            }
    }
    __syncthreads();

    int d = (t < 256) ? hist[t] : 0;
    if (t < 256) sc[t] = d;
    __syncthreads();
    for (int off = 1; off < 256; off <<= 1) {
        int u = (t < 256 && t >= off) ? sc[t - off] : 0;
        __syncthreads();
        if (t < 256) sc[t] += u;
        __syncthreads();
    }
    int sbase = b * CAP_PAD;
    if (t < 256) {
        int excl = sc[t] - d;
        float dv = rsqrtf((float)(d + 1));
        disL[t] = dv;
        int n = (b << 8) + t;
        if (n < NN) {
            dis[n] = dv;
            offs[n] = sbase + excl;
            ends[n] = sbase + sc[t];     // start + own degree
        }
        lcur[t] = excl;
    }
    __syncthreads();
    for (int j = t; j < cnt; j += 512) {
        unsigned int rec = stage[j];
        int slot = atomicAdd(&lcur[rec & 255u], 1);
        srcs[sbase + slot] = (int)(rec >> 8);
    }
    // epilogue: scale this bucket's xwsh rows by dis (coalesced u32 r/m/w)
    int n0 = b << 8;
    for (int idx = t; idx < 256 * 16; idx += 512) {
        int loc = idx >> 4;
        int n = n0 + loc;
        if (n >= NN) break;
        uint_t* p = (uint_t*)(xwsh + ((size_t)n << 5)) + (idx & 15);
        uint_t v = *p;
        float dv = disL[loc];
        float lo = h2f((ushort_t)(v & 0xffffu)) * dv;
        float hi = h2f((ushort_t)(v >> 16)) * dv;
        *p = (uint_t)f2h_u(lo) | ((uint_t)f2h_u(hi) << 16);
    }
}

// ===========================================================================
// k3: aggregate, zero-reduce layout, fully batched (no serial remainder).
// Half-wave (32 lanes) = one node; lane owns one output dim. Every 8-edge
// round: 8 independent srcs reads + 8 independent xwsh gathers; tail lanes
// clamp to e-1 and mask the accumulate.
// ===========================================================================
__global__ __launch_bounds__(256)
void aggregate_kernel(const int* __restrict__ offs, const int* __restrict__ ends,
                      const int* __restrict__ srcs,
                      const float* __restrict__ dis, const ushort_t* __restrict__ xwsh,
                      const float* __restrict__ bias, float* __restrict__ out) {
    int gw = (int)((blockIdx.x * (long long)blockDim.x + threadIdx.x) >> 6);
    int half = (threadIdx.x >> 5) & 1;
    int wid = gw * 2 + half;
    if (wid >= NN) return;
    int d = threadIdx.x & 31;

    int s = offs[wid], e = ends[wid];
    float acc = h2f(xwsh[((size_t)wid << 5) + d]);   // self-loop (scaled)
    for (int i = s; i < e; i += 8) {
        int r[8];
        ushort_t u[8];
#pragma unroll
        for (int k = 0; k < 8; ++k) {
            int j = i + k;
            r[k] = srcs[j < e ? j : e - 1];
        }
#pragma unroll
        for (int k = 0; k < 8; ++k) u[k] = xwsh[((size_t)r[k] << 5) + d];
#pragma unroll
        for (int k = 0; k < 8; ++k) acc += (i + k < e) ? h2f(u[k]) : 0.f;
    }
    out[((size_t)wid << 5) + d] = dis[wid] * acc + bias[d];
}

// ===========================================================================
// Fallback path (R1) if workspace is too small
// ===========================================================================
__global__ void deg_count_kernel(const int* __restrict__ col, int* __restrict__ deg) {
    int e = blockIdx.x * blockDim.x + threadIdx.x;
    if (e < NE) atomicAdd(&deg[col[e]], 1);
}
__global__ void dis_kernel(const int* __restrict__ deg, float* __restrict__ dis) {
    int i = blockIdx.x * blockDim.x + threadIdx.x;
    if (i < NN) dis[i] = rsqrtf((float)(deg[i] + 1));
}
__global__ void xw_init_kernel(const float* __restrict__ x, const float* __restrict__ W,
                               const float* __restrict__ b, const float* __restrict__ dis,
                               float* __restrict__ xw, float* __restrict__ out) {
    __shared__ float Ws[DIN * DOUT];
    for (int i = threadIdx.x; i < DIN * DOUT; i += blockDim.x) Ws[i] = W[i];
    __syncthreads();
    int idx = blockIdx.x * blockDim.x + threadIdx.x;
    if (idx >= NN * DOUT) return;
    int n = idx >> 5;
    int d = idx & (DOUT - 1);
    const float* xr = x + (long long)n * DIN;
    float acc = 0.f;
#pragma unroll
    for (int k = 0; k < DIN; ++k) acc += xr[k] * Ws[k * DOUT + d];
    xw[idx] = acc;
    float di = dis[n];
    out[idx] = di * di * acc + b[d];
}
__global__ void scatter_kernel(const int* __restrict__ row, const int* __restrict__ col,
                               const float* __restrict__ dis, const float* __restrict__ xw,
                               float* __restrict__ out) {
    long long idx = (long long)blockIdx.x * blockDim.x + threadIdx.x;
    if (idx >= (long long)NE * DOUT) return;
    int e = (int)(idx >> 5);
    int d = (int)(idx & (DOUT - 1));
    int r = row[e];
    int c = col[e];
    atomicAdd(&out[c * DOUT + d], dis[r] * dis[c] * xw[r * DOUT + d]);
}

// ===========================================================================
extern "C" void kernel_launch(void* const* d_in, const int* in_sizes, int n_in,
                              void* d_out, int out_size, void* d_ws, size_t ws_size,
                              hipStream_t stream) {
    const float* x  = (const float*)d_in[0];
    const int*   ei = (const int*)d_in[1];
    const float* W  = (const float*)d_in[2];
    const float* b  = (const float*)d_in[3];
    float* out = (float*)d_out;

    const int* row = ei;       // edge_index[0] = source
    const int* col = ei + NE;  // edge_index[1] = target

    char* ws = (char*)d_ws;
    int*          histmat = (int*)(ws + 0);          //   802,816 B (512*392*4)
    int*          offs    = (int*)(ws + 802816);     //   400,000 B
    int*          ends    = (int*)(ws + 1202816);    //   400,000 B
    float*        dis     = (float*)(ws + 1602816);  //   400,000 B
    unsigned int* records = (unsigned int*)(ws + 2002816);  // 6,400,000 B
    int*          srcs    = (int*)(ws + 8402816);    // 391*4608*4 = 7,206,912 B
    ushort_t*     xwsh    = (ushort_t*)(ws + 15609728);     // 6,400,000 B
    const size_t WS_NEEDED = 22009728ull;

    if (ws_size >= WS_NEEDED) {
        fill_xw_kernel<<<FILLB + XWB, 512, 0, stream>>>(row, col, histmat,
                                                        records, x, W, xwsh);
        sort_kernel<<<NBUK, 512, 0, stream>>>(histmat, records, srcs, dis,
                                              offs, ends, xwsh);
        {
            long long waves = (NN + 1) / 2;             // 2 nodes per wave
            int bl = (int)((waves + 3) / 4);            // 4 waves per block
            aggregate_kernel<<<bl, 256, 0, stream>>>(offs, ends, srcs, dis, xwsh, b, out);
        }
    } else {
        // fallback: atomic scatter path
        int* deg2 = (int*)(ws + 0);
        float* dis2 = (float*)(ws + 400128);
        float* xw = (float*)(ws + 800256);
        hipMemsetAsync(deg2, 0, NN * sizeof(int), stream);
        {
            int th = 256, bl = (NE + th - 1) / th;
            deg_count_kernel<<<bl, th, 0, stream>>>(col, deg2);
        }
        {
            int th = 256, bl = (NN + th - 1) / th;
            dis_kernel<<<bl, th, 0, stream>>>(deg2, dis2);
        }
        {
            long long total = (long long)NN * DOUT;
            int bl = (int)((total + 255) / 256);
            xw_init_kernel<<<bl, 256, 0, stream>>>(x, W, b, dis2, xw, out);
        }
        {
            long long total = (long long)NE * DOUT;
            int bl = (int)((total + 255) / 256);
            scatter_kernel<<<bl, 256, 0, stream>>>(row, col, dis2, xw, out);
        }
    }
}